// Round 7
// baseline (1034.409 us; speedup 1.0000x reference)
//
#include <hip/hip_runtime.h>
#include <hip/hip_fp16.h>

#define NN 100000
#define NE 1600000
#define NBATCH 512
#define NEG 0.2f
#define NBUK 391        // ceil(NN/256): bucket = dst >> 8
#define BCAP 6144       // bucket capacity; E[load]=4096, sigma=64 -> +32 sigma

// ---------------------------------------------------------------------------
// GATConv (4 heads x 16, self-loops, softmax over dst) -> SAGPool score
// (GraphConv linear) -> global_add_pool.
// R7 = R4 resubmit (three infra flakes in a row, no counters yet).
// Destination-bucketed edge staging: edges packed 4B ((dst&255)<<17|src)
// into per-bucket regions; each bucket (256 dst nodes) builds its CSR in LDS
// and runs the GAT softmax+aggregate from LDS — no global elist at all.
// Score via linearity: score[n] = sum_in p[src] + r[n] + b, p = x_gat.w_rel,
// accumulated per-bucket in LDS (no global float atomics).
// ---------------------------------------------------------------------------

__global__ void k_init(int* __restrict__ gcount) {
  int i = blockIdx.x * 256 + threadIdx.x;
  if (i < NBUK) gcount[i] = 0;
}

// h16 = fp16(x @ W)  (100000x64 @ 64x64), plus per-head attention dots (fp32)
__global__ __launch_bounds__(256) void k_gemm(
    const float* __restrict__ x, const float* __restrict__ W,
    const float* __restrict__ att_src, const float* __restrict__ att_dst,
    __half* __restrict__ h16, float* __restrict__ a_src,
    float* __restrict__ a_dst) {
  __shared__ float Ws[64 * 64];
  int tid = threadIdx.x;
#pragma unroll
  for (int i = 0; i < 16; ++i) Ws[i * 256 + tid] = W[i * 256 + tid];
  __syncthreads();
  int lane = tid & 63;
  int wid = tid >> 6;
  float atts = att_src[lane];
  float attd = att_dst[lane];
  int base = blockIdx.x * 16 + wid * 4;          // NN % 16 == 0
  const float4* x0 = (const float4*)(x + (size_t)base * 64);
  const float4* x1 = x0 + 16;
  const float4* x2 = x0 + 32;
  const float4* x3 = x0 + 48;
  float s0 = 0.f, s1 = 0.f, s2 = 0.f, s3 = 0.f;
#pragma unroll
  for (int k4 = 0; k4 < 16; ++k4) {
    float4 a = x0[k4], b = x1[k4], c = x2[k4], d = x3[k4];
#pragma unroll
    for (int j = 0; j < 4; ++j) {
      float wv = Ws[(k4 * 4 + j) * 64 + lane];
      s0 = fmaf(((const float*)&a)[j], wv, s0);
      s1 = fmaf(((const float*)&b)[j], wv, s1);
      s2 = fmaf(((const float*)&c)[j], wv, s2);
      s3 = fmaf(((const float*)&d)[j], wv, s3);
    }
  }
  int ob = base * 64 + lane;
  h16[ob]       = __float2half(s0);
  h16[ob + 64]  = __float2half(s1);
  h16[ob + 128] = __float2half(s2);
  h16[ob + 192] = __float2half(s3);

  int head = lane >> 4;
  bool wr = (lane & 15) == 0;
#define RED16(v)                                                               \
  do {                                                                         \
    v += __shfl_xor(v, 1);                                                     \
    v += __shfl_xor(v, 2);                                                     \
    v += __shfl_xor(v, 4);                                                     \
    v += __shfl_xor(v, 8);                                                     \
  } while (0)
  float v;
  v = s0 * atts; RED16(v); if (wr) a_src[(base + 0) * 4 + head] = v;
  v = s0 * attd; RED16(v); if (wr) a_dst[(base + 0) * 4 + head] = v;
  v = s1 * atts; RED16(v); if (wr) a_src[(base + 1) * 4 + head] = v;
  v = s1 * attd; RED16(v); if (wr) a_dst[(base + 1) * 4 + head] = v;
  v = s2 * atts; RED16(v); if (wr) a_src[(base + 2) * 4 + head] = v;
  v = s2 * attd; RED16(v); if (wr) a_dst[(base + 2) * 4 + head] = v;
  v = s3 * atts; RED16(v); if (wr) a_src[(base + 3) * 4 + head] = v;
  v = s3 * attd; RED16(v); if (wr) a_dst[(base + 3) * 4 + head] = v;
#undef RED16
}

// bucket edges by dst>>8; entry packs (dst&255)<<17 | src  (src < 2^17)
__global__ void k_bucket(const int* __restrict__ ei, int* __restrict__ gcount,
                         int* __restrict__ buf) {
  int e = blockIdx.x * 256 + threadIdx.x;
  if (e >= NE) return;
  int s = ei[e];
  int d = ei[NE + e];
  int b = d >> 8;
  int pos = atomicAdd(&gcount[b], 1);
  if (pos < BCAP) buf[b * BCAP + pos] = ((d & 255) << 17) | s;
}

// Per-bucket: build local CSR in LDS, then GAT softmax+aggregate (wave/node).
__global__ __launch_bounds__(256) void k_gatb(
    const int* __restrict__ gcount, const int* __restrict__ buf,
    const __half* __restrict__ h16, const float* __restrict__ a_src,
    const float* __restrict__ a_dst, const float* __restrict__ bias,
    const float* __restrict__ w_rel, const float* __restrict__ w_root,
    const float* __restrict__ b_score, float* __restrict__ out_x,
    float* __restrict__ p, float* __restrict__ score) {
  __shared__ int ldeg[256];
  __shared__ int loff[256];
  __shared__ int lcur[256];
  __shared__ int lel[BCAP];
  __shared__ int wsum[4];
  int bk = blockIdx.x;
  int tid = threadIdx.x;
  int lane = tid & 63, wid = tid >> 6;
  int n0 = bk << 8;
  int nnodes = NN - n0; if (nnodes > 256) nnodes = 256;
  int c = gcount[bk]; if (c > BCAP) c = BCAP;

  ldeg[tid] = 0;
  __syncthreads();
  for (int i = tid; i < c; i += 256)
    atomicAdd(&ldeg[buf[bk * BCAP + i] >> 17], 1);
  __syncthreads();
  // exclusive scan of ldeg -> loff (shfl within wave, wave partials via LDS)
  int v = ldeg[tid];
  int inc = v;
#pragma unroll
  for (int o = 1; o < 64; o <<= 1) {
    int t = __shfl_up(inc, o);
    if (lane >= o) inc += t;
  }
  if (lane == 63) wsum[wid] = inc;
  __syncthreads();
  int basew = 0;
  for (int k = 0; k < wid; ++k) basew += wsum[k];
  int myoff = basew + inc - v;
  loff[tid] = myoff;
  lcur[tid] = myoff;
  __syncthreads();
  for (int i = tid; i < c; i += 256) {
    int entry = buf[bk * BCAP + i];
    int pos = atomicAdd(&lcur[entry >> 17], 1);
    lel[pos] = entry & 0x1FFFF;
  }
  __syncthreads();

  // GAT phase: one wave per node, round-robin
  int hsel = lane & 3;           // head, weight phase
  int esel = lane >> 2;          // edge slot, weight phase (0..15)
  int hl = lane & 31;            // feature-pair index
  int epar = lane >> 5;          // parallel-edge half in accum phase
  int ohead = hl >> 3;           // head owning feats 2hl,2hl+1
  for (int nl = wid; nl < nnodes; nl += 4) {
    int node = n0 + nl;
    int dg = ldeg[nl];
    int off = loff[nl];
    float ad = a_dst[node * 4 + hsel];
    float acc_x, acc_y, zacc;
    {  // self-loop
      float l = a_src[node * 4 + hsel] + ad;
      l = l > 0.f ? l : NEG * l;
      float e = __expf(l);
      zacc = (esel == 0) ? e : 0.f;
      float lo = a_src[node * 4 + ohead] + a_dst[node * 4 + ohead];
      lo = lo > 0.f ? lo : NEG * lo;
      float eo = __expf(lo);
      __half2 hv = *reinterpret_cast<const __half2*>(h16 + node * 64 + 2 * hl);
      acc_x = (epar == 0) ? eo * __low2float(hv) : 0.f;
      acc_y = (epar == 0) ? eo * __high2float(hv) : 0.f;
    }
    for (int cb = 0; cb < dg; cb += 64) {
      int rem = dg - cb; if (rem > 64) rem = 64;
      int s_lane = (lane < rem) ? lel[off + cb + lane] : 0;
      for (int base = 0; base < rem; base += 16) {
        // weights for 16 edges x 4 heads, lane-parallel
        int e = base + esel;
        int srcw = __shfl(s_lane, e < 63 ? e : 63);
        float w = 0.f;
        if (e < rem) {
          float l = a_src[srcw * 4 + hsel] + ad;
          l = l > 0.f ? l : NEG * l;
          w = __expf(l);
        }
        zacc += w;
        // accumulate 2 edges/iter (half2 rows)
        int nrem = rem - base; if (nrem > 16) nrem = 16;
        for (int j = 0; j < nrem; j += 2) {
          int jj = j + epar;
          float wj = __shfl(w, jj * 4 + ohead);
          int sj = __shfl(s_lane, base + jj);
          __half2 hv = *reinterpret_cast<const __half2*>(h16 + sj * 64 + 2 * hl);
          acc_x = fmaf(wj, __low2float(hv), acc_x);
          acc_y = fmaf(wj, __high2float(hv), acc_y);
        }
      }
    }
    // merge edge halves; z across edge-slot dim
    acc_x += __shfl_xor(acc_x, 32);
    acc_y += __shfl_xor(acc_y, 32);
    zacc += __shfl_xor(zacc, 4);
    zacc += __shfl_xor(zacc, 8);
    zacc += __shfl_xor(zacc, 16);
    zacc += __shfl_xor(zacc, 32);
    float z = __shfl(zacc, ohead);

    float2 bv = ((const float2*)bias)[hl];
    float xgx = acc_x / z + bv.x;
    float xgy = acc_y / z + bv.y;
    float2 wrv = ((const float2*)w_rel)[hl];
    float2 wov = ((const float2*)w_root)[hl];
    float pp = xgx * wrv.x + xgy * wrv.y;
    float rr = xgx * wov.x + xgy * wov.y;
#pragma unroll
    for (int o = 1; o < 32; o <<= 1) {
      pp += __shfl_xor(pp, o);
      rr += __shfl_xor(rr, o);
    }
    if (lane == 0) {
      p[node] = pp;
      score[node] = rr + b_score[0];
    }
    if (epar == 0) {
      float2 xg = {xgx, xgy};
      *reinterpret_cast<float2*>(out_x + node * 64 + 2 * hl) = xg;
    }
  }
}

// score[dst] += sum_in p[src], per-bucket in LDS — no global atomics.
__global__ __launch_bounds__(256) void k_scat2(const int* __restrict__ gcount,
                                               const int* __restrict__ buf,
                                               const float* __restrict__ p,
                                               float* __restrict__ score) {
  __shared__ float sacc[256];
  int bk = blockIdx.x;
  int tid = threadIdx.x;
  sacc[tid] = 0.f;
  __syncthreads();
  int c = gcount[bk]; if (c > BCAP) c = BCAP;
  for (int i = tid; i < c; i += 256) {
    int entry = buf[bk * BCAP + i];
    atomicAdd(&sacc[entry >> 17], p[entry & 0x1FFFF]);
  }
  __syncthreads();
  int n = (bk << 8) + tid;
  if (n < NN) score[n] += sacc[tid];
}

__device__ inline int lower_bound_i(const int* a, int n, int key) {
  int lo = 0, hi = n;
  while (lo < hi) {
    int mid = (lo + hi) >> 1;
    if (a[mid] < key) lo = mid + 1; else hi = mid;
  }
  return lo;
}

// one block per graph; batch is sorted. gout = (sum e*x)/(sum e).
__global__ __launch_bounds__(256) void k_pool(const float* __restrict__ xg,
                                              const float* __restrict__ score,
                                              const int* __restrict__ batch,
                                              float* __restrict__ gout) {
  int b = blockIdx.x;
  int lo = lower_bound_i(batch, NN, b);
  int hi = lower_bound_i(batch, NN, b + 1);
  int lane = threadIdx.x & 63;
  int w = threadIdx.x >> 6;
  float z = 0.f, vec = 0.f;
  for (int i = lo + w; i < hi; i += 4) {
    float e = __expf(score[i]);
    z += e;
    vec = fmaf(e, xg[(size_t)i * 64 + lane], vec);
  }
  __shared__ float zs[4];
  __shared__ float vs[4][64];
  if (lane == 0) zs[w] = z;
  vs[w][lane] = vec;
  __syncthreads();
  if (w == 0) {
    float zt = zs[0] + zs[1] + zs[2] + zs[3];
    float vt = vs[0][lane] + vs[1][lane] + vs[2][lane] + vs[3][lane];
    gout[(size_t)b * 64 + lane] = (hi > lo) ? vt / zt : 0.f;
  }
}

extern "C" void kernel_launch(void* const* d_in, const int* in_sizes, int n_in,
                              void* d_out, int out_size, void* d_ws,
                              size_t ws_size, hipStream_t stream) {
  (void)in_sizes; (void)n_in; (void)out_size; (void)ws_size;
  const float* x       = (const float*)d_in[0];
  const int*   ei      = (const int*)d_in[1];
  const int*   batch   = (const int*)d_in[2];
  const float* W       = (const float*)d_in[3];
  const float* att_src = (const float*)d_in[4];
  const float* att_dst = (const float*)d_in[5];
  const float* bias    = (const float*)d_in[6];
  const float* w_rel   = (const float*)d_in[7];
  const float* w_root  = (const float*)d_in[8];
  const float* b_score = (const float*)d_in[9];

  float* out_x = (float*)d_out;
  float* gout  = out_x + (size_t)NN * 64;

  char* wsp = (char*)d_ws;
  __half* h16  = (__half*)wsp; wsp += (size_t)NN * 64 * 2;
  float* a_src = (float*)wsp;  wsp += (size_t)NN * 4 * 4;
  float* a_dst = (float*)wsp;  wsp += (size_t)NN * 4 * 4;
  float* p     = (float*)wsp;  wsp += (size_t)NN * 4;
  float* score = (float*)wsp;  wsp += (size_t)NN * 4;
  int*   gcnt  = (int*)wsp;    wsp += (size_t)((NBUK + 127) / 128) * 128 * 4;
  int*   buf   = (int*)wsp;    wsp += (size_t)NBUK * BCAP * 4;

  dim3 blk(256);
  k_init<<<2, blk, 0, stream>>>(gcnt);
  k_gemm<<<NN / 16, blk, 0, stream>>>(x, W, att_src, att_dst, h16, a_src, a_dst);
  k_bucket<<<(NE + 255) / 256, blk, 0, stream>>>(ei, gcnt, buf);
  k_gatb<<<NBUK, blk, 0, stream>>>(gcnt, buf, h16, a_src, a_dst, bias,
                                   w_rel, w_root, b_score, out_x, p, score);
  k_scat2<<<NBUK, blk, 0, stream>>>(gcnt, buf, p, score);
  k_pool<<<NBATCH, blk, 0, stream>>>(out_x, score, batch, gout);
}

// Round 8
// 297.596 us; speedup vs baseline: 3.4759x; 3.4759x over previous
//
#include <hip/hip_runtime.h>
#include <hip/hip_fp16.h>

#define NN 100000
#define NE 1600000
#define NBATCH 512
#define NEG 0.2f
#define NBUK 391        // ceil(NN/256): bucket = dst >> 8
#define BCAP 6144       // bucket capacity; E[load]=4096, sigma=64 -> +32 sigma
#define CHUNK 4096      // edges per bucketing block
#define NCHB ((NE + CHUNK - 1) / CHUNK)   // 391

// ---------------------------------------------------------------------------
// GATConv (4 heads x 16, self-loops, softmax over dst) -> SAGPool score
// (GraphConv linear) -> global_add_pool.
// R8: R7 post-mortem showed k_bucket's per-edge atomics on 391 hot counters
// serialize (558us, 1.6% BW). Replaced with chunked two-pass bucketing:
// per-block LDS histogram -> ONE batched global atomic per touched bucket
// (153k total, 26 edges amortized each) -> LDS-cursor scatter (clustered
// writes). k_gatb/k_scat2 widened to 1024 threads (16 waves/block) to fix
// gather-latency hiding (R7: only 4 waves/block).
// ---------------------------------------------------------------------------

__global__ void k_init(int* __restrict__ gcount) {
  int i = blockIdx.x * 256 + threadIdx.x;
  if (i < NBUK) gcount[i] = 0;
}

// h16 = fp16(x @ W)  (100000x64 @ 64x64), plus per-head attention dots (fp32)
__global__ __launch_bounds__(256) void k_gemm(
    const float* __restrict__ x, const float* __restrict__ W,
    const float* __restrict__ att_src, const float* __restrict__ att_dst,
    __half* __restrict__ h16, float* __restrict__ a_src,
    float* __restrict__ a_dst) {
  __shared__ float Ws[64 * 64];
  int tid = threadIdx.x;
#pragma unroll
  for (int i = 0; i < 16; ++i) Ws[i * 256 + tid] = W[i * 256 + tid];
  __syncthreads();
  int lane = tid & 63;
  int wid = tid >> 6;
  float atts = att_src[lane];
  float attd = att_dst[lane];
  int base = blockIdx.x * 16 + wid * 4;          // NN % 16 == 0
  const float4* x0 = (const float4*)(x + (size_t)base * 64);
  const float4* x1 = x0 + 16;
  const float4* x2 = x0 + 32;
  const float4* x3 = x0 + 48;
  float s0 = 0.f, s1 = 0.f, s2 = 0.f, s3 = 0.f;
#pragma unroll
  for (int k4 = 0; k4 < 16; ++k4) {
    float4 a = x0[k4], b = x1[k4], c = x2[k4], d = x3[k4];
#pragma unroll
    for (int j = 0; j < 4; ++j) {
      float wv = Ws[(k4 * 4 + j) * 64 + lane];
      s0 = fmaf(((const float*)&a)[j], wv, s0);
      s1 = fmaf(((const float*)&b)[j], wv, s1);
      s2 = fmaf(((const float*)&c)[j], wv, s2);
      s3 = fmaf(((const float*)&d)[j], wv, s3);
    }
  }
  int ob = base * 64 + lane;
  h16[ob]       = __float2half(s0);
  h16[ob + 64]  = __float2half(s1);
  h16[ob + 128] = __float2half(s2);
  h16[ob + 192] = __float2half(s3);

  int head = lane >> 4;
  bool wr = (lane & 15) == 0;
#define RED16(v)                                                               \
  do {                                                                         \
    v += __shfl_xor(v, 1);                                                     \
    v += __shfl_xor(v, 2);                                                     \
    v += __shfl_xor(v, 4);                                                     \
    v += __shfl_xor(v, 8);                                                     \
  } while (0)
  float v;
  v = s0 * atts; RED16(v); if (wr) a_src[(base + 0) * 4 + head] = v;
  v = s0 * attd; RED16(v); if (wr) a_dst[(base + 0) * 4 + head] = v;
  v = s1 * atts; RED16(v); if (wr) a_src[(base + 1) * 4 + head] = v;
  v = s1 * attd; RED16(v); if (wr) a_dst[(base + 1) * 4 + head] = v;
  v = s2 * atts; RED16(v); if (wr) a_src[(base + 2) * 4 + head] = v;
  v = s2 * attd; RED16(v); if (wr) a_dst[(base + 2) * 4 + head] = v;
  v = s3 * atts; RED16(v); if (wr) a_src[(base + 3) * 4 + head] = v;
  v = s3 * attd; RED16(v); if (wr) a_dst[(base + 3) * 4 + head] = v;
#undef RED16
}

// Chunked two-pass bucketer: LDS histogram -> one global atomic per touched
// bucket -> LDS-cursor scatter. Entry packs (dst&255)<<17 | src (src < 2^17).
__global__ __launch_bounds__(1024) void k_cf2(const int* __restrict__ ei,
                                              int* __restrict__ gcount,
                                              int* __restrict__ buf) {
  __shared__ int hist[NBUK];
  int blk = blockIdx.x;
  int tid = threadIdx.x;
  int e0 = blk * CHUNK;
  int e1 = e0 + CHUNK; if (e1 > NE) e1 = NE;
  for (int i = tid; i < NBUK; i += 1024) hist[i] = 0;
  __syncthreads();
  for (int i = e0 + tid; i < e1; i += 1024)
    atomicAdd(&hist[ei[NE + i] >> 8], 1);
  __syncthreads();
  for (int i = tid; i < NBUK; i += 1024) {
    int hc = hist[i];
    hist[i] = hc ? atomicAdd(&gcount[i], hc) : 0;   // batched reservation
  }
  __syncthreads();
  for (int i = e0 + tid; i < e1; i += 1024) {
    int s = ei[i];
    int d = ei[NE + i];
    int b = d >> 8;
    int pos = atomicAdd(&hist[b], 1);               // LDS cursor
    if (pos < BCAP) buf[b * BCAP + pos] = ((d & 255) << 17) | s;
  }
}

// Per-bucket: build local CSR in LDS, then GAT softmax+aggregate.
// 1024 threads = 16 waves; one wave per node round-robin.
__global__ __launch_bounds__(1024) void k_gatb(
    const int* __restrict__ gcount, const int* __restrict__ buf,
    const __half* __restrict__ h16, const float* __restrict__ a_src,
    const float* __restrict__ a_dst, const float* __restrict__ bias,
    const float* __restrict__ w_rel, const float* __restrict__ w_root,
    const float* __restrict__ b_score, float* __restrict__ out_x,
    float* __restrict__ p, float* __restrict__ score) {
  __shared__ int ldeg[256];
  __shared__ int loff[256];
  __shared__ int lcur[256];
  __shared__ int lel[BCAP];
  __shared__ int wsum[4];
  int bk = blockIdx.x;
  int tid = threadIdx.x;
  int lane = tid & 63, wid = tid >> 6;
  int n0 = bk << 8;
  int nnodes = NN - n0; if (nnodes > 256) nnodes = 256;
  int c = gcount[bk]; if (c > BCAP) c = BCAP;

  if (tid < 256) ldeg[tid] = 0;
  __syncthreads();
  for (int i = tid; i < c; i += 1024)
    atomicAdd(&ldeg[buf[bk * BCAP + i] >> 17], 1);
  __syncthreads();
  // exclusive scan of ldeg -> loff (first 4 waves only; wave-uniform branch)
  if (tid < 256) {
    int v = ldeg[tid];
    int inc = v;
#pragma unroll
    for (int o = 1; o < 64; o <<= 1) {
      int t = __shfl_up(inc, o);
      if (lane >= o) inc += t;
    }
    if (lane == 63) wsum[wid] = inc;
    // stash for after the barrier
    lcur[tid] = inc - v;   // wave-local exclusive prefix
  }
  __syncthreads();
  if (tid < 256) {
    int basew = 0;
    for (int k = 0; k < wid; ++k) basew += wsum[k];
    int myoff = basew + lcur[tid];
    loff[tid] = myoff;
    lcur[tid] = myoff;
  }
  __syncthreads();
  for (int i = tid; i < c; i += 1024) {
    int entry = buf[bk * BCAP + i];
    int pos = atomicAdd(&lcur[entry >> 17], 1);
    lel[pos] = entry & 0x1FFFF;
  }
  __syncthreads();

  // GAT phase: one wave per node, 16 waves round-robin
  int hsel = lane & 3;           // head, weight phase
  int esel = lane >> 2;          // edge slot, weight phase (0..15)
  int hl = lane & 31;            // feature-pair index
  int epar = lane >> 5;          // parallel-edge half in accum phase
  int ohead = hl >> 3;           // head owning feats 2hl,2hl+1
  for (int nl = wid; nl < nnodes; nl += 16) {
    int node = n0 + nl;
    int dg = ldeg[nl];
    int off = loff[nl];
    float ad = a_dst[node * 4 + hsel];
    float acc_x, acc_y, zacc;
    {  // self-loop
      float l = a_src[node * 4 + hsel] + ad;
      l = l > 0.f ? l : NEG * l;
      float e = __expf(l);
      zacc = (esel == 0) ? e : 0.f;
      float lo = a_src[node * 4 + ohead] + a_dst[node * 4 + ohead];
      lo = lo > 0.f ? lo : NEG * lo;
      float eo = __expf(lo);
      __half2 hv = *reinterpret_cast<const __half2*>(h16 + node * 64 + 2 * hl);
      acc_x = (epar == 0) ? eo * __low2float(hv) : 0.f;
      acc_y = (epar == 0) ? eo * __high2float(hv) : 0.f;
    }
    for (int cb = 0; cb < dg; cb += 64) {
      int rem = dg - cb; if (rem > 64) rem = 64;
      int s_lane = (lane < rem) ? lel[off + cb + lane] : 0;
      for (int base = 0; base < rem; base += 16) {
        // weights for 16 edges x 4 heads, lane-parallel
        int e = base + esel;
        int srcw = __shfl(s_lane, e < 63 ? e : 63);
        float w = 0.f;
        if (e < rem) {
          float l = a_src[srcw * 4 + hsel] + ad;
          l = l > 0.f ? l : NEG * l;
          w = __expf(l);
        }
        zacc += w;
        // accumulate 2 edges/iter (half2 rows)
        int nrem = rem - base; if (nrem > 16) nrem = 16;
        for (int j = 0; j < nrem; j += 2) {
          int jj = j + epar;
          float wj = __shfl(w, jj * 4 + ohead);
          int sj = __shfl(s_lane, base + jj);
          __half2 hv = *reinterpret_cast<const __half2*>(h16 + sj * 64 + 2 * hl);
          acc_x = fmaf(wj, __low2float(hv), acc_x);
          acc_y = fmaf(wj, __high2float(hv), acc_y);
        }
      }
    }
    // merge edge halves; z across edge-slot dim
    acc_x += __shfl_xor(acc_x, 32);
    acc_y += __shfl_xor(acc_y, 32);
    zacc += __shfl_xor(zacc, 4);
    zacc += __shfl_xor(zacc, 8);
    zacc += __shfl_xor(zacc, 16);
    zacc += __shfl_xor(zacc, 32);
    float z = __shfl(zacc, ohead);

    float2 bv = ((const float2*)bias)[hl];
    float xgx = acc_x / z + bv.x;
    float xgy = acc_y / z + bv.y;
    float2 wrv = ((const float2*)w_rel)[hl];
    float2 wov = ((const float2*)w_root)[hl];
    float pp = xgx * wrv.x + xgy * wrv.y;
    float rr = xgx * wov.x + xgy * wov.y;
#pragma unroll
    for (int o = 1; o < 32; o <<= 1) {
      pp += __shfl_xor(pp, o);
      rr += __shfl_xor(rr, o);
    }
    if (lane == 0) {
      p[node] = pp;
      score[node] = rr + b_score[0];
    }
    if (epar == 0) {
      float2 xg = {xgx, xgy};
      *reinterpret_cast<float2*>(out_x + node * 64 + 2 * hl) = xg;
    }
  }
}

// score[dst] += sum_in p[src], per-bucket in LDS — no global atomics.
__global__ __launch_bounds__(1024) void k_scat2(const int* __restrict__ gcount,
                                                const int* __restrict__ buf,
                                                const float* __restrict__ p,
                                                float* __restrict__ score) {
  __shared__ float sacc[256];
  int bk = blockIdx.x;
  int tid = threadIdx.x;
  if (tid < 256) sacc[tid] = 0.f;
  __syncthreads();
  int c = gcount[bk]; if (c > BCAP) c = BCAP;
  for (int i = tid; i < c; i += 1024) {
    int entry = buf[bk * BCAP + i];
    atomicAdd(&sacc[entry >> 17], p[entry & 0x1FFFF]);
  }
  __syncthreads();
  int n = (bk << 8) + tid;
  if (tid < 256 && n < NN) score[n] += sacc[tid];
}

__device__ inline int lower_bound_i(const int* a, int n, int key) {
  int lo = 0, hi = n;
  while (lo < hi) {
    int mid = (lo + hi) >> 1;
    if (a[mid] < key) lo = mid + 1; else hi = mid;
  }
  return lo;
}

// one block per graph; batch is sorted. gout = (sum e*x)/(sum e).
__global__ __launch_bounds__(256) void k_pool(const float* __restrict__ xg,
                                              const float* __restrict__ score,
                                              const int* __restrict__ batch,
                                              float* __restrict__ gout) {
  int b = blockIdx.x;
  int lo = lower_bound_i(batch, NN, b);
  int hi = lower_bound_i(batch, NN, b + 1);
  int lane = threadIdx.x & 63;
  int w = threadIdx.x >> 6;
  float z = 0.f, vec = 0.f;
  for (int i = lo + w; i < hi; i += 4) {
    float e = __expf(score[i]);
    z += e;
    vec = fmaf(e, xg[(size_t)i * 64 + lane], vec);
  }
  __shared__ float zs[4];
  __shared__ float vs[4][64];
  if (lane == 0) zs[w] = z;
  vs[w][lane] = vec;
  __syncthreads();
  if (w == 0) {
    float zt = zs[0] + zs[1] + zs[2] + zs[3];
    float vt = vs[0][lane] + vs[1][lane] + vs[2][lane] + vs[3][lane];
    gout[(size_t)b * 64 + lane] = (hi > lo) ? vt / zt : 0.f;
  }
}

extern "C" void kernel_launch(void* const* d_in, const int* in_sizes, int n_in,
                              void* d_out, int out_size, void* d_ws,
                              size_t ws_size, hipStream_t stream) {
  (void)in_sizes; (void)n_in; (void)out_size; (void)ws_size;
  const float* x       = (const float*)d_in[0];
  const int*   ei      = (const int*)d_in[1];
  const int*   batch   = (const int*)d_in[2];
  const float* W       = (const float*)d_in[3];
  const float* att_src = (const float*)d_in[4];
  const float* att_dst = (const float*)d_in[5];
  const float* bias    = (const float*)d_in[6];
  const float* w_rel   = (const float*)d_in[7];
  const float* w_root  = (const float*)d_in[8];
  const float* b_score = (const float*)d_in[9];

  float* out_x = (float*)d_out;
  float* gout  = out_x + (size_t)NN * 64;

  char* wsp = (char*)d_ws;
  __half* h16  = (__half*)wsp; wsp += (size_t)NN * 64 * 2;
  float* a_src = (float*)wsp;  wsp += (size_t)NN * 4 * 4;
  float* a_dst = (float*)wsp;  wsp += (size_t)NN * 4 * 4;
  float* p     = (float*)wsp;  wsp += (size_t)NN * 4;
  float* score = (float*)wsp;  wsp += (size_t)NN * 4;
  int*   gcnt  = (int*)wsp;    wsp += (size_t)((NBUK + 127) / 128) * 128 * 4;
  int*   buf   = (int*)wsp;    wsp += (size_t)NBUK * BCAP * 4;

  k_init<<<2, 256, 0, stream>>>(gcnt);
  k_gemm<<<NN / 16, 256, 0, stream>>>(x, W, att_src, att_dst, h16, a_src,
                                      a_dst);
  k_cf2<<<NCHB, 1024, 0, stream>>>(ei, gcnt, buf);
  k_gatb<<<NBUK, 1024, 0, stream>>>(gcnt, buf, h16, a_src, a_dst, bias,
                                    w_rel, w_root, b_score, out_x, p, score);
  k_scat2<<<NBUK, 1024, 0, stream>>>(gcnt, buf, p, score);
  k_pool<<<NBATCH, 256, 0, stream>>>(out_x, score, batch, gout);
}

// Round 10
// 281.322 us; speedup vs baseline: 3.6770x; 1.0578x over previous
//
#include <hip/hip_runtime.h>
#include <hip/hip_fp16.h>

#define NN 100000
#define NE 1600000
#define NBATCH 512
#define NEG 0.2f
#define NBUK 782        // ceil(NN/128): bucket = dst >> 7
#define BCAP 3456       // E[load]=2048, sigma=45 -> +31 sigma, clamped anyway
#define CHUNK 4096      // edges per bucketing block
#define NCHB ((NE + CHUNK - 1) / CHUNK)   // 391

// ---------------------------------------------------------------------------
// GATConv (4 heads x 16, self-loops, softmax over dst) -> SAGPool score
// (GraphConv linear) -> global_add_pool.
// R10 = R9 resubmit (infra timeout, kernel never ran).
// R9 rationale: R8 showed k_gatb latency-bound at 56% occupancy (16-wave
// blocks, 2/CU max) with 1 gather in flight per lane. Halved bucket to 128
// dst nodes (782 x 512-thread blocks, 15.4KB LDS -> 4 blocks/CU) and gave
// the accum loop two independent fma/gather chains (4 edges per iteration).
// ---------------------------------------------------------------------------

__global__ void k_init(int* __restrict__ gcount) {
  int i = threadIdx.x;
  if (i < NBUK) gcount[i] = 0;
}

// h16 = fp16(x @ W)  (100000x64 @ 64x64), plus per-head attention dots (fp32)
__global__ __launch_bounds__(256) void k_gemm(
    const float* __restrict__ x, const float* __restrict__ W,
    const float* __restrict__ att_src, const float* __restrict__ att_dst,
    __half* __restrict__ h16, float* __restrict__ a_src,
    float* __restrict__ a_dst) {
  __shared__ float Ws[64 * 64];
  int tid = threadIdx.x;
#pragma unroll
  for (int i = 0; i < 16; ++i) Ws[i * 256 + tid] = W[i * 256 + tid];
  __syncthreads();
  int lane = tid & 63;
  int wid = tid >> 6;
  float atts = att_src[lane];
  float attd = att_dst[lane];
  int base = blockIdx.x * 16 + wid * 4;          // NN % 16 == 0
  const float4* x0 = (const float4*)(x + (size_t)base * 64);
  const float4* x1 = x0 + 16;
  const float4* x2 = x0 + 32;
  const float4* x3 = x0 + 48;
  float s0 = 0.f, s1 = 0.f, s2 = 0.f, s3 = 0.f;
#pragma unroll
  for (int k4 = 0; k4 < 16; ++k4) {
    float4 a = x0[k4], b = x1[k4], c = x2[k4], d = x3[k4];
#pragma unroll
    for (int j = 0; j < 4; ++j) {
      float wv = Ws[(k4 * 4 + j) * 64 + lane];
      s0 = fmaf(((const float*)&a)[j], wv, s0);
      s1 = fmaf(((const float*)&b)[j], wv, s1);
      s2 = fmaf(((const float*)&c)[j], wv, s2);
      s3 = fmaf(((const float*)&d)[j], wv, s3);
    }
  }
  int ob = base * 64 + lane;
  h16[ob]       = __float2half(s0);
  h16[ob + 64]  = __float2half(s1);
  h16[ob + 128] = __float2half(s2);
  h16[ob + 192] = __float2half(s3);

  int head = lane >> 4;
  bool wr = (lane & 15) == 0;
#define RED16(v)                                                               \
  do {                                                                         \
    v += __shfl_xor(v, 1);                                                     \
    v += __shfl_xor(v, 2);                                                     \
    v += __shfl_xor(v, 4);                                                     \
    v += __shfl_xor(v, 8);                                                     \
  } while (0)
  float v;
  v = s0 * atts; RED16(v); if (wr) a_src[(base + 0) * 4 + head] = v;
  v = s0 * attd; RED16(v); if (wr) a_dst[(base + 0) * 4 + head] = v;
  v = s1 * atts; RED16(v); if (wr) a_src[(base + 1) * 4 + head] = v;
  v = s1 * attd; RED16(v); if (wr) a_dst[(base + 1) * 4 + head] = v;
  v = s2 * atts; RED16(v); if (wr) a_src[(base + 2) * 4 + head] = v;
  v = s2 * attd; RED16(v); if (wr) a_dst[(base + 2) * 4 + head] = v;
  v = s3 * atts; RED16(v); if (wr) a_src[(base + 3) * 4 + head] = v;
  v = s3 * attd; RED16(v); if (wr) a_dst[(base + 3) * 4 + head] = v;
#undef RED16
}

// Chunked two-pass bucketer: LDS histogram -> one batched global atomic per
// touched bucket -> LDS-cursor scatter. Entry: (dst&127)<<17 | src (src<2^17).
__global__ __launch_bounds__(1024) void k_cf2(const int* __restrict__ ei,
                                              int* __restrict__ gcount,
                                              int* __restrict__ buf) {
  __shared__ int hist[NBUK];
  int blk = blockIdx.x;
  int tid = threadIdx.x;
  int e0 = blk * CHUNK;
  int e1 = e0 + CHUNK; if (e1 > NE) e1 = NE;
  for (int i = tid; i < NBUK; i += 1024) hist[i] = 0;
  __syncthreads();
  for (int i = e0 + tid; i < e1; i += 1024)
    atomicAdd(&hist[ei[NE + i] >> 7], 1);
  __syncthreads();
  for (int i = tid; i < NBUK; i += 1024) {
    int hc = hist[i];
    hist[i] = hc ? atomicAdd(&gcount[i], hc) : 0;   // batched reservation
  }
  __syncthreads();
  for (int i = e0 + tid; i < e1; i += 1024) {
    int s = ei[i];
    int d = ei[NE + i];
    int b = d >> 7;
    int pos = atomicAdd(&hist[b], 1);               // LDS cursor
    if (pos < BCAP) buf[b * BCAP + pos] = ((d & 127) << 17) | s;
  }
}

// Per-bucket (128 dst nodes): build local CSR in LDS, then GAT softmax+agg.
// 512 threads = 8 waves; one wave per node round-robin.
__global__ __launch_bounds__(512) void k_gatb(
    const int* __restrict__ gcount, const int* __restrict__ buf,
    const __half* __restrict__ h16, const float* __restrict__ a_src,
    const float* __restrict__ a_dst, const float* __restrict__ bias,
    const float* __restrict__ w_rel, const float* __restrict__ w_root,
    const float* __restrict__ b_score, float* __restrict__ out_x,
    float* __restrict__ p, float* __restrict__ score) {
  __shared__ int ldeg[128];
  __shared__ int loff[128];
  __shared__ int lcur[128];
  __shared__ int lel[BCAP];
  __shared__ int wsum[2];
  int bk = blockIdx.x;
  int tid = threadIdx.x;
  int lane = tid & 63, wid = tid >> 6;   // wid 0..7
  int n0 = bk << 7;
  int nnodes = NN - n0; if (nnodes > 128) nnodes = 128;
  int c = gcount[bk]; if (c > BCAP) c = BCAP;

  if (tid < 128) ldeg[tid] = 0;
  __syncthreads();
  for (int i = tid; i < c; i += 512)
    atomicAdd(&ldeg[buf[bk * BCAP + i] >> 17], 1);
  __syncthreads();
  // exclusive scan of ldeg[128] -> loff (first 2 waves; wave-uniform branch)
  if (tid < 128) {
    int v = ldeg[tid];
    int inc = v;
#pragma unroll
    for (int o = 1; o < 64; o <<= 1) {
      int t = __shfl_up(inc, o);
      if (lane >= o) inc += t;
    }
    if (lane == 63) wsum[wid] = inc;
    lcur[tid] = inc - v;   // wave-local exclusive prefix (stash)
  }
  __syncthreads();
  if (tid < 128) {
    int myoff = ((wid == 1) ? wsum[0] : 0) + lcur[tid];
    loff[tid] = myoff;
    lcur[tid] = myoff;
  }
  __syncthreads();
  for (int i = tid; i < c; i += 512) {
    int entry = buf[bk * BCAP + i];
    int pos = atomicAdd(&lcur[entry >> 17], 1);
    lel[pos] = entry & 0x1FFFF;
  }
  __syncthreads();

  // GAT phase: one wave per node, 8 waves round-robin
  int hsel = lane & 3;           // head, weight phase
  int esel = lane >> 2;          // edge slot, weight phase (0..15)
  int hl = lane & 31;            // feature-pair index
  int epar = lane >> 5;          // parallel-edge half in accum phase
  int ohead = hl >> 3;           // head owning feats 2hl,2hl+1
  for (int nl = wid; nl < nnodes; nl += 8) {
    int node = n0 + nl;
    int dg = ldeg[nl];
    int off = loff[nl];
    float ad = a_dst[node * 4 + hsel];
    float acc_x, acc_y, acc_x2 = 0.f, acc_y2 = 0.f, zacc;
    {  // self-loop
      float l = a_src[node * 4 + hsel] + ad;
      l = l > 0.f ? l : NEG * l;
      float e = __expf(l);
      zacc = (esel == 0) ? e : 0.f;
      float lo = a_src[node * 4 + ohead] + a_dst[node * 4 + ohead];
      lo = lo > 0.f ? lo : NEG * lo;
      float eo = __expf(lo);
      __half2 hv = *reinterpret_cast<const __half2*>(h16 + node * 64 + 2 * hl);
      acc_x = (epar == 0) ? eo * __low2float(hv) : 0.f;
      acc_y = (epar == 0) ? eo * __high2float(hv) : 0.f;
    }
    for (int cb = 0; cb < dg; cb += 64) {
      int rem = dg - cb; if (rem > 64) rem = 64;
      int s_lane = (lane < rem) ? lel[off + cb + lane] : 0;
      for (int gb = 0; gb < rem; gb += 16) {
        // weights for 16 edges x 4 heads, lane-parallel
        int e = gb + esel;                 // <= 63
        int srcw = __shfl(s_lane, e);
        float w = 0.f;
        if (e < rem) {
          float l = a_src[srcw * 4 + hsel] + ad;
          l = l > 0.f ? l : NEG * l;
          w = __expf(l);
        }
        zacc += w;
        // accumulate 4 edges/iter: two independent gather+fma chains.
        // j0 <= 13, j1 <= 15 always; out-of-range slots carry w == 0.
        int nrem = rem - gb; if (nrem > 16) nrem = 16;
        for (int j = 0; j < nrem; j += 4) {
          int j0 = j + epar;
          int j1 = j + 2 + epar;
          float w0 = __shfl(w, j0 * 4 + ohead);
          float w1 = __shfl(w, j1 * 4 + ohead);
          int s0 = __shfl(s_lane, gb + j0);
          int s1 = __shfl(s_lane, gb + j1);
          __half2 hv0 = *reinterpret_cast<const __half2*>(h16 + s0 * 64 + 2 * hl);
          __half2 hv1 = *reinterpret_cast<const __half2*>(h16 + s1 * 64 + 2 * hl);
          acc_x = fmaf(w0, __low2float(hv0), acc_x);
          acc_y = fmaf(w0, __high2float(hv0), acc_y);
          acc_x2 = fmaf(w1, __low2float(hv1), acc_x2);
          acc_y2 = fmaf(w1, __high2float(hv1), acc_y2);
        }
      }
    }
    acc_x += acc_x2;
    acc_y += acc_y2;
    // merge edge halves; z across edge-slot dim
    acc_x += __shfl_xor(acc_x, 32);
    acc_y += __shfl_xor(acc_y, 32);
    zacc += __shfl_xor(zacc, 4);
    zacc += __shfl_xor(zacc, 8);
    zacc += __shfl_xor(zacc, 16);
    zacc += __shfl_xor(zacc, 32);
    float z = __shfl(zacc, ohead);

    float2 bv = ((const float2*)bias)[hl];
    float xgx = acc_x / z + bv.x;
    float xgy = acc_y / z + bv.y;
    float2 wrv = ((const float2*)w_rel)[hl];
    float2 wov = ((const float2*)w_root)[hl];
    float pp = xgx * wrv.x + xgy * wrv.y;
    float rr = xgx * wov.x + xgy * wov.y;
#pragma unroll
    for (int o = 1; o < 32; o <<= 1) {
      pp += __shfl_xor(pp, o);
      rr += __shfl_xor(rr, o);
    }
    if (lane == 0) {
      p[node] = pp;
      score[node] = rr + b_score[0];
    }
    if (epar == 0) {
      float2 xg = {xgx, xgy};
      *reinterpret_cast<float2*>(out_x + node * 64 + 2 * hl) = xg;
    }
  }
}

// score[dst] += sum_in p[src], per-bucket in LDS — no global atomics.
__global__ __launch_bounds__(512) void k_scat2(const int* __restrict__ gcount,
                                               const int* __restrict__ buf,
                                               const float* __restrict__ p,
                                               float* __restrict__ score) {
  __shared__ float sacc[128];
  int bk = blockIdx.x;
  int tid = threadIdx.x;
  if (tid < 128) sacc[tid] = 0.f;
  __syncthreads();
  int c = gcount[bk]; if (c > BCAP) c = BCAP;
  for (int i = tid; i < c; i += 512) {
    int entry = buf[bk * BCAP + i];
    atomicAdd(&sacc[entry >> 17], p[entry & 0x1FFFF]);
  }
  __syncthreads();
  int n = (bk << 7) + tid;
  if (tid < 128 && n < NN) score[n] += sacc[tid];
}

__device__ inline int lower_bound_i(const int* a, int n, int key) {
  int lo = 0, hi = n;
  while (lo < hi) {
    int mid = (lo + hi) >> 1;
    if (a[mid] < key) lo = mid + 1; else hi = mid;
  }
  return lo;
}

// one block per graph; batch is sorted. gout = (sum e*x)/(sum e).
__global__ __launch_bounds__(256) void k_pool(const float* __restrict__ xg,
                                              const float* __restrict__ score,
                                              const int* __restrict__ batch,
                                              float* __restrict__ gout) {
  int b = blockIdx.x;
  int lo = lower_bound_i(batch, NN, b);
  int hi = lower_bound_i(batch, NN, b + 1);
  int lane = threadIdx.x & 63;
  int w = threadIdx.x >> 6;
  float z = 0.f, vec = 0.f;
  for (int i = lo + w; i < hi; i += 4) {
    float e = __expf(score[i]);
    z += e;
    vec = fmaf(e, xg[(size_t)i * 64 + lane], vec);
  }
  __shared__ float zs[4];
  __shared__ float vs[4][64];
  if (lane == 0) zs[w] = z;
  vs[w][lane] = vec;
  __syncthreads();
  if (w == 0) {
    float zt = zs[0] + zs[1] + zs[2] + zs[3];
    float vt = vs[0][lane] + vs[1][lane] + vs[2][lane] + vs[3][lane];
    gout[(size_t)b * 64 + lane] = (hi > lo) ? vt / zt : 0.f;
  }
}

extern "C" void kernel_launch(void* const* d_in, const int* in_sizes, int n_in,
                              void* d_out, int out_size, void* d_ws,
                              size_t ws_size, hipStream_t stream) {
  (void)in_sizes; (void)n_in; (void)out_size; (void)ws_size;
  const float* x       = (const float*)d_in[0];
  const int*   ei      = (const int*)d_in[1];
  const int*   batch   = (const int*)d_in[2];
  const float* W       = (const float*)d_in[3];
  const float* att_src = (const float*)d_in[4];
  const float* att_dst = (const float*)d_in[5];
  const float* bias    = (const float*)d_in[6];
  const float* w_rel   = (const float*)d_in[7];
  const float* w_root  = (const float*)d_in[8];
  const float* b_score = (const float*)d_in[9];

  float* out_x = (float*)d_out;
  float* gout  = out_x + (size_t)NN * 64;

  char* wsp = (char*)d_ws;
  __half* h16  = (__half*)wsp; wsp += (size_t)NN * 64 * 2;
  float* a_src = (float*)wsp;  wsp += (size_t)NN * 4 * 4;
  float* a_dst = (float*)wsp;  wsp += (size_t)NN * 4 * 4;
  float* p     = (float*)wsp;  wsp += (size_t)NN * 4;
  float* score = (float*)wsp;  wsp += (size_t)NN * 4;
  int*   gcnt  = (int*)wsp;    wsp += (size_t)((NBUK + 127) / 128) * 128 * 4;
  int*   buf   = (int*)wsp;    wsp += (size_t)NBUK * BCAP * 4;

  k_init<<<1, 1024, 0, stream>>>(gcnt);
  k_gemm<<<NN / 16, 256, 0, stream>>>(x, W, att_src, att_dst, h16, a_src,
                                      a_dst);
  k_cf2<<<NCHB, 1024, 0, stream>>>(ei, gcnt, buf);
  k_gatb<<<NBUK, 512, 0, stream>>>(gcnt, buf, h16, a_src, a_dst, bias,
                                   w_rel, w_root, b_score, out_x, p, score);
  k_scat2<<<NBUK, 512, 0, stream>>>(gcnt, buf, p, score);
  k_pool<<<NBATCH, 256, 0, stream>>>(out_x, score, batch, gout);
}

// Round 11
// 264.677 us; speedup vs baseline: 3.9082x; 1.0629x over previous
//
#include <hip/hip_runtime.h>
#include <hip/hip_fp16.h>

#define NN 100000
#define NE 1600000
#define NBATCH 512
#define NEG 0.2f
#define NBUK 782        // staging buckets: dst >> 7 (128 dst nodes each)
#define BCAP 3456       // bucket capacity; E=2048, sigma=45 -> +31 sigma
#define BC2 2048        // half-bucket lel capacity; E=1024, sigma=32
#define CHUNK 4096
#define NCHB ((NE + CHUNK - 1) / CHUNK)   // 391
#define NGEMMB ((NN + 63) / 64)           // 1563

// ---------------------------------------------------------------------------
// GATConv (4 heads x 16, self-loops, softmax over dst) -> SAGPool score
// (GraphConv linear) -> global_add_pool.
// R11: (a) k_gatb now runs 2 blocks per staging bucket (64 dst nodes each,
// 256 thr, ~9KB LDS -> 6.1 blocks/CU) with 4 independent gather chains
// (8 edges/iter) — R10 showed 51% occupancy, latency-bound gather.
// (b) k_gemm + k_cf2 fused into one block-range dispatch (independent work,
// overlap + one less gap). (c) k_init replaced by hipMemsetAsync.
// ---------------------------------------------------------------------------

// ---- fused: blocks [0,NGEMMB) do GEMM (64 rows), rest do edge bucketing ----
__global__ __launch_bounds__(1024) void k_gc(
    const float* __restrict__ x, const float* __restrict__ W,
    const float* __restrict__ att_src, const float* __restrict__ att_dst,
    __half* __restrict__ h16, float* __restrict__ a_src,
    float* __restrict__ a_dst, const int* __restrict__ ei,
    int* __restrict__ gcount, int* __restrict__ buf) {
  if (blockIdx.x < NGEMMB) {
    // ---------------- GEMM part: 64 rows/block, 16 waves ----------------
    __shared__ float Ws[64 * 64];
    int tid = threadIdx.x;
#pragma unroll
    for (int i = 0; i < 4; ++i) Ws[i * 1024 + tid] = W[i * 1024 + tid];
    __syncthreads();
    int lane = tid & 63;
    int wid = tid >> 6;                    // 0..15
    int base = blockIdx.x * 64 + wid * 4;  // 4 rows per wave
    if (base >= NN) return;                // uniform per wave; after barrier
    float atts = att_src[lane];
    float attd = att_dst[lane];
    const float4* x0 = (const float4*)(x + (size_t)base * 64);
    const float4* x1 = x0 + 16;
    const float4* x2 = x0 + 32;
    const float4* x3 = x0 + 48;
    float s0 = 0.f, s1 = 0.f, s2 = 0.f, s3 = 0.f;
#pragma unroll
    for (int k4 = 0; k4 < 16; ++k4) {
      float4 a = x0[k4], b = x1[k4], c = x2[k4], d = x3[k4];
#pragma unroll
      for (int j = 0; j < 4; ++j) {
        float wv = Ws[(k4 * 4 + j) * 64 + lane];
        s0 = fmaf(((const float*)&a)[j], wv, s0);
        s1 = fmaf(((const float*)&b)[j], wv, s1);
        s2 = fmaf(((const float*)&c)[j], wv, s2);
        s3 = fmaf(((const float*)&d)[j], wv, s3);
      }
    }
    int ob = base * 64 + lane;
    h16[ob]       = __float2half(s0);
    h16[ob + 64]  = __float2half(s1);
    h16[ob + 128] = __float2half(s2);
    h16[ob + 192] = __float2half(s3);
    int head = lane >> 4;
    bool wr = (lane & 15) == 0;
#define RED16(v)                                                               \
    do {                                                                       \
      v += __shfl_xor(v, 1);                                                   \
      v += __shfl_xor(v, 2);                                                   \
      v += __shfl_xor(v, 4);                                                   \
      v += __shfl_xor(v, 8);                                                   \
    } while (0)
    float v;
    v = s0 * atts; RED16(v); if (wr) a_src[(base + 0) * 4 + head] = v;
    v = s0 * attd; RED16(v); if (wr) a_dst[(base + 0) * 4 + head] = v;
    v = s1 * atts; RED16(v); if (wr) a_src[(base + 1) * 4 + head] = v;
    v = s1 * attd; RED16(v); if (wr) a_dst[(base + 1) * 4 + head] = v;
    v = s2 * atts; RED16(v); if (wr) a_src[(base + 2) * 4 + head] = v;
    v = s2 * attd; RED16(v); if (wr) a_dst[(base + 2) * 4 + head] = v;
    v = s3 * atts; RED16(v); if (wr) a_src[(base + 3) * 4 + head] = v;
    v = s3 * attd; RED16(v); if (wr) a_dst[(base + 3) * 4 + head] = v;
#undef RED16
  } else {
    // ---------------- bucketing part: chunked two-pass ----------------
    __shared__ int hist[NBUK];
    int blk = blockIdx.x - NGEMMB;
    int tid = threadIdx.x;
    int e0 = blk * CHUNK;
    int e1 = e0 + CHUNK; if (e1 > NE) e1 = NE;
    for (int i = tid; i < NBUK; i += 1024) hist[i] = 0;
    __syncthreads();
    for (int i = e0 + tid; i < e1; i += 1024)
      atomicAdd(&hist[ei[NE + i] >> 7], 1);
    __syncthreads();
    for (int i = tid; i < NBUK; i += 1024) {
      int hc = hist[i];
      hist[i] = hc ? atomicAdd(&gcount[i], hc) : 0;  // batched reservation
    }
    __syncthreads();
    for (int i = e0 + tid; i < e1; i += 1024) {
      int s = ei[i];
      int d = ei[NE + i];
      int b = d >> 7;
      int pos = atomicAdd(&hist[b], 1);              // LDS cursor
      if (pos < BCAP) buf[b * BCAP + pos] = ((d & 127) << 17) | s;
    }
  }
}

// Per half-bucket (64 dst nodes): build local CSR in LDS, GAT softmax+agg.
// grid = 2*NBUK; 256 threads = 4 waves; one wave per node round-robin.
__global__ __launch_bounds__(256) void k_gatb(
    const int* __restrict__ gcount, const int* __restrict__ buf,
    const __half* __restrict__ h16, const float* __restrict__ a_src,
    const float* __restrict__ a_dst, const float* __restrict__ bias,
    const float* __restrict__ w_rel, const float* __restrict__ w_root,
    const float* __restrict__ b_score, float* __restrict__ out_x,
    float* __restrict__ p, float* __restrict__ score) {
  __shared__ int ldeg[64];
  __shared__ int loff[64];
  __shared__ int lcur[64];
  __shared__ int lel[BC2];
  int bk = blockIdx.x >> 1;
  int half = blockIdx.x & 1;
  int tid = threadIdx.x;
  int lane = tid & 63, wid = tid >> 6;   // wid 0..3
  int n0 = (bk << 7) + (half << 6);
  int nnodes = NN - n0;
  if (nnodes <= 0) return;               // whole block exits (bk 781 half 1)
  if (nnodes > 64) nnodes = 64;
  int c = gcount[bk]; if (c > BCAP) c = BCAP;

  if (tid < 64) ldeg[tid] = 0;
  __syncthreads();
  for (int i = tid; i < c; i += 256) {
    int r = buf[bk * BCAP + i] >> 17;
    if ((r >> 6) == half) atomicAdd(&ldeg[r & 63], 1);
  }
  __syncthreads();
  // single-wave exclusive scan of ldeg[64]
  if (tid < 64) {
    int v = ldeg[tid];
    int inc = v;
#pragma unroll
    for (int o = 1; o < 64; o <<= 1) {
      int t = __shfl_up(inc, o);
      if (lane >= o) inc += t;
    }
    loff[tid] = inc - v;
    lcur[tid] = inc - v;
  }
  __syncthreads();
  for (int i = tid; i < c; i += 256) {
    int entry = buf[bk * BCAP + i];
    int r = entry >> 17;
    if ((r >> 6) == half) {
      int pos = atomicAdd(&lcur[r & 63], 1);
      if (pos < BC2) lel[pos] = entry & 0x1FFFF;
    }
  }
  __syncthreads();

  // GAT phase: one wave per node, 4 waves round-robin
  int hsel = lane & 3;           // head, weight phase
  int esel = lane >> 2;          // edge slot, weight phase (0..15)
  int hl = lane & 31;            // feature-pair index
  int epar = lane >> 5;          // parallel-edge half in accum phase
  int ohead = hl >> 3;           // head owning feats 2hl,2hl+1
  for (int nl = wid; nl < nnodes; nl += 4) {
    int node = n0 + nl;
    int dg = ldeg[nl];
    int off = loff[nl];
    if (off + dg > BC2) dg = (BC2 > off) ? BC2 - off : 0;  // safety clamp
    float ad = a_dst[node * 4 + hsel];
    float ax0, ay0, ax1 = 0.f, ay1 = 0.f, ax2 = 0.f, ay2 = 0.f,
          ax3 = 0.f, ay3 = 0.f, zacc;
    {  // self-loop
      float l = a_src[node * 4 + hsel] + ad;
      l = l > 0.f ? l : NEG * l;
      float e = __expf(l);
      zacc = (esel == 0) ? e : 0.f;
      float lo = a_src[node * 4 + ohead] + a_dst[node * 4 + ohead];
      lo = lo > 0.f ? lo : NEG * lo;
      float eo = __expf(lo);
      __half2 hv = *reinterpret_cast<const __half2*>(h16 + node * 64 + 2 * hl);
      ax0 = (epar == 0) ? eo * __low2float(hv) : 0.f;
      ay0 = (epar == 0) ? eo * __high2float(hv) : 0.f;
    }
    for (int cb = 0; cb < dg; cb += 64) {
      int rem = dg - cb; if (rem > 64) rem = 64;
      int s_lane = (lane < rem) ? lel[off + cb + lane] : 0;
      for (int gb = 0; gb < rem; gb += 16) {
        // weights for 16 edges x 4 heads, lane-parallel
        int e = gb + esel;                 // <= 63
        int srcw = __shfl(s_lane, e);
        float w = 0.f;
        if (e < rem) {
          float l = a_src[srcw * 4 + hsel] + ad;
          l = l > 0.f ? l : NEG * l;
          w = __expf(l);
        }
        zacc += w;
        // accumulate 8 edges/iter: 4 independent gather+fma chains.
        // j3 = j+6+epar <= 15; OOR slots carry w == 0; s_lane[pad] = 0.
        int nrem = rem - gb; if (nrem > 16) nrem = 16;
        for (int j = 0; j < nrem; j += 8) {
          int j0 = j + epar, j1 = j + 2 + epar, j2 = j + 4 + epar,
              j3 = j + 6 + epar;
          float w0 = __shfl(w, j0 * 4 + ohead);
          float w1 = __shfl(w, j1 * 4 + ohead);
          float w2 = __shfl(w, j2 * 4 + ohead);
          float w3 = __shfl(w, j3 * 4 + ohead);
          int s0 = __shfl(s_lane, gb + j0);
          int s1 = __shfl(s_lane, gb + j1);
          int s2 = __shfl(s_lane, gb + j2);
          int s3 = __shfl(s_lane, gb + j3);
          __half2 hv0 = *reinterpret_cast<const __half2*>(h16 + s0 * 64 + 2 * hl);
          __half2 hv1 = *reinterpret_cast<const __half2*>(h16 + s1 * 64 + 2 * hl);
          __half2 hv2 = *reinterpret_cast<const __half2*>(h16 + s2 * 64 + 2 * hl);
          __half2 hv3 = *reinterpret_cast<const __half2*>(h16 + s3 * 64 + 2 * hl);
          ax0 = fmaf(w0, __low2float(hv0), ax0);
          ay0 = fmaf(w0, __high2float(hv0), ay0);
          ax1 = fmaf(w1, __low2float(hv1), ax1);
          ay1 = fmaf(w1, __high2float(hv1), ay1);
          ax2 = fmaf(w2, __low2float(hv2), ax2);
          ay2 = fmaf(w2, __high2float(hv2), ay2);
          ax3 = fmaf(w3, __low2float(hv3), ax3);
          ay3 = fmaf(w3, __high2float(hv3), ay3);
        }
      }
    }
    float acc_x = (ax0 + ax1) + (ax2 + ax3);
    float acc_y = (ay0 + ay1) + (ay2 + ay3);
    // merge edge halves; z across edge-slot dim
    acc_x += __shfl_xor(acc_x, 32);
    acc_y += __shfl_xor(acc_y, 32);
    zacc += __shfl_xor(zacc, 4);
    zacc += __shfl_xor(zacc, 8);
    zacc += __shfl_xor(zacc, 16);
    zacc += __shfl_xor(zacc, 32);
    float z = __shfl(zacc, ohead);

    float2 bv = ((const float2*)bias)[hl];
    float xgx = acc_x / z + bv.x;
    float xgy = acc_y / z + bv.y;
    float2 wrv = ((const float2*)w_rel)[hl];
    float2 wov = ((const float2*)w_root)[hl];
    float pp = xgx * wrv.x + xgy * wrv.y;
    float rr = xgx * wov.x + xgy * wov.y;
#pragma unroll
    for (int o = 1; o < 32; o <<= 1) {
      pp += __shfl_xor(pp, o);
      rr += __shfl_xor(rr, o);
    }
    if (lane == 0) {
      p[node] = pp;
      score[node] = rr + b_score[0];
    }
    if (epar == 0) {
      float2 xg = {xgx, xgy};
      *reinterpret_cast<float2*>(out_x + node * 64 + 2 * hl) = xg;
    }
  }
}

// score[dst] += sum_in p[src], per-bucket in LDS — no global atomics.
__global__ __launch_bounds__(512) void k_scat2(const int* __restrict__ gcount,
                                               const int* __restrict__ buf,
                                               const float* __restrict__ p,
                                               float* __restrict__ score) {
  __shared__ float sacc[128];
  int bk = blockIdx.x;
  int tid = threadIdx.x;
  if (tid < 128) sacc[tid] = 0.f;
  __syncthreads();
  int c = gcount[bk]; if (c > BCAP) c = BCAP;
  for (int i = tid; i < c; i += 512) {
    int entry = buf[bk * BCAP + i];
    atomicAdd(&sacc[entry >> 17], p[entry & 0x1FFFF]);
  }
  __syncthreads();
  int n = (bk << 7) + tid;
  if (tid < 128 && n < NN) score[n] += sacc[tid];
}

__device__ inline int lower_bound_i(const int* a, int n, int key) {
  int lo = 0, hi = n;
  while (lo < hi) {
    int mid = (lo + hi) >> 1;
    if (a[mid] < key) lo = mid + 1; else hi = mid;
  }
  return lo;
}

// one block per graph; batch is sorted. gout = (sum e*x)/(sum e).
__global__ __launch_bounds__(256) void k_pool(const float* __restrict__ xg,
                                              const float* __restrict__ score,
                                              const int* __restrict__ batch,
                                              float* __restrict__ gout) {
  int b = blockIdx.x;
  int lo = lower_bound_i(batch, NN, b);
  int hi = lower_bound_i(batch, NN, b + 1);
  int lane = threadIdx.x & 63;
  int w = threadIdx.x >> 6;
  float z = 0.f, vec = 0.f;
  for (int i = lo + w; i < hi; i += 4) {
    float e = __expf(score[i]);
    z += e;
    vec = fmaf(e, xg[(size_t)i * 64 + lane], vec);
  }
  __shared__ float zs[4];
  __shared__ float vs[4][64];
  if (lane == 0) zs[w] = z;
  vs[w][lane] = vec;
  __syncthreads();
  if (w == 0) {
    float zt = zs[0] + zs[1] + zs[2] + zs[3];
    float vt = vs[0][lane] + vs[1][lane] + vs[2][lane] + vs[3][lane];
    gout[(size_t)b * 64 + lane] = (hi > lo) ? vt / zt : 0.f;
  }
}

extern "C" void kernel_launch(void* const* d_in, const int* in_sizes, int n_in,
                              void* d_out, int out_size, void* d_ws,
                              size_t ws_size, hipStream_t stream) {
  (void)in_sizes; (void)n_in; (void)out_size; (void)ws_size;
  const float* x       = (const float*)d_in[0];
  const int*   ei      = (const int*)d_in[1];
  const int*   batch   = (const int*)d_in[2];
  const float* W       = (const float*)d_in[3];
  const float* att_src = (const float*)d_in[4];
  const float* att_dst = (const float*)d_in[5];
  const float* bias    = (const float*)d_in[6];
  const float* w_rel   = (const float*)d_in[7];
  const float* w_root  = (const float*)d_in[8];
  const float* b_score = (const float*)d_in[9];

  float* out_x = (float*)d_out;
  float* gout  = out_x + (size_t)NN * 64;

  char* wsp = (char*)d_ws;
  __half* h16  = (__half*)wsp; wsp += (size_t)NN * 64 * 2;
  float* a_src = (float*)wsp;  wsp += (size_t)NN * 4 * 4;
  float* a_dst = (float*)wsp;  wsp += (size_t)NN * 4 * 4;
  float* p     = (float*)wsp;  wsp += (size_t)NN * 4;
  float* score = (float*)wsp;  wsp += (size_t)NN * 4;
  int*   gcnt  = (int*)wsp;    wsp += (size_t)((NBUK + 127) / 128) * 128 * 4;
  int*   buf   = (int*)wsp;    wsp += (size_t)NBUK * BCAP * 4;

  hipMemsetAsync(gcnt, 0, NBUK * sizeof(int), stream);
  k_gc<<<NGEMMB + NCHB, 1024, 0, stream>>>(x, W, att_src, att_dst, h16,
                                           a_src, a_dst, ei, gcnt, buf);
  k_gatb<<<2 * NBUK, 256, 0, stream>>>(gcnt, buf, h16, a_src, a_dst, bias,
                                       w_rel, w_root, b_score, out_x, p, score);
  k_scat2<<<NBUK, 512, 0, stream>>>(gcnt, buf, p, score);
  k_pool<<<NBATCH, 256, 0, stream>>>(out_x, score, batch, gout);
}

// Round 13
// 261.171 us; speedup vs baseline: 3.9607x; 1.0134x over previous
//
#include <hip/hip_runtime.h>
#include <hip/hip_fp16.h>

#define NN 100000
#define NE 1600000
#define NBATCH 512
#define NEG 0.2f
#define NBUK 782        // staging buckets: dst >> 7 (128 dst nodes each)
#define BCAP 3456       // bucket capacity; E=2048, sigma=45 -> +31 sigma
#define BC2 2048        // half-bucket lel capacity; E=1024, sigma=32
#define CHUNK 8192
#define NCHB ((NE + CHUNK - 1) / CHUNK)   // 196
#define NGEMMB ((NN + 63) / 64)           // 1563
#define RPT ((BCAP + 255) / 256)          // 14

// ---------------------------------------------------------------------------
// GATConv (4 heads x 16, self-loops, softmax over dst) -> SAGPool score
// (GraphConv linear) -> global_add_pool.
// R13 = R12 resubmit (infra timeout, kernel never ran).
// R12 rationale: R11 showed fused k_gc at 78-84us, VALU 17% / HBM 8% /
// occ 41% — straggling bucket blocks scheduled AFTER 1563 gemm blocks.
// (a) bucket blocks first in the grid; (b) CHUNK 8192 (196 blocks, half the
// fixed phase overhead); (c) edges held in registers across the two bucket
// passes (no ei re-read); (d) k_gatb reads its buf slice once into regs.
// ---------------------------------------------------------------------------

// ---- fused: blocks [0,NCHB) bucket edges; [NCHB, NCHB+NGEMMB) do GEMM ----
__global__ __launch_bounds__(1024) void k_gc(
    const float* __restrict__ x, const float* __restrict__ W,
    const float* __restrict__ att_src, const float* __restrict__ att_dst,
    __half* __restrict__ h16, float* __restrict__ a_src,
    float* __restrict__ a_dst, const int* __restrict__ ei,
    int* __restrict__ gcount, int* __restrict__ buf) {
  if (blockIdx.x < NCHB) {
    // ------------- bucketing: two-pass, edges held in registers -------------
    __shared__ int hist[NBUK];
    int blk = blockIdx.x;
    int tid = threadIdx.x;
    int e0 = blk * CHUNK;
    int e1 = e0 + CHUNK; if (e1 > NE) e1 = NE;
    if (tid < NBUK) hist[tid] = 0;
    __syncthreads();
    int s8[8], d8[8];
#pragma unroll
    for (int k = 0; k < 8; ++k) {
      int idx = e0 + tid + k * 1024;
      if (idx < e1) {
        s8[k] = ei[idx];
        d8[k] = ei[NE + idx];
      } else {
        d8[k] = -1;
        s8[k] = 0;
      }
    }
#pragma unroll
    for (int k = 0; k < 8; ++k)
      if (d8[k] >= 0) atomicAdd(&hist[d8[k] >> 7], 1);
    __syncthreads();
    if (tid < NBUK) {
      int hc = hist[tid];
      hist[tid] = hc ? atomicAdd(&gcount[tid], hc) : 0;  // batched reservation
    }
    __syncthreads();
#pragma unroll
    for (int k = 0; k < 8; ++k) {
      if (d8[k] >= 0) {
        int b = d8[k] >> 7;
        int pos = atomicAdd(&hist[b], 1);                // LDS cursor
        if (pos < BCAP) buf[b * BCAP + pos] = ((d8[k] & 127) << 17) | s8[k];
      }
    }
  } else {
    // ---------------- GEMM part: 64 rows/block, 16 waves ----------------
    __shared__ float Ws[64 * 64];
    int tid = threadIdx.x;
#pragma unroll
    for (int i = 0; i < 4; ++i) Ws[i * 1024 + tid] = W[i * 1024 + tid];
    __syncthreads();
    int lane = tid & 63;
    int wid = tid >> 6;                              // 0..15
    int base = (blockIdx.x - NCHB) * 64 + wid * 4;   // 4 rows per wave
    if (base >= NN) return;                // wave-uniform; no barriers after
    float atts = att_src[lane];
    float attd = att_dst[lane];
    const float4* x0 = (const float4*)(x + (size_t)base * 64);
    const float4* x1 = x0 + 16;
    const float4* x2 = x0 + 32;
    const float4* x3 = x0 + 48;
    float s0 = 0.f, s1 = 0.f, s2 = 0.f, s3 = 0.f;
#pragma unroll
    for (int k4 = 0; k4 < 16; ++k4) {
      float4 a = x0[k4], b = x1[k4], c = x2[k4], d = x3[k4];
#pragma unroll
      for (int j = 0; j < 4; ++j) {
        float wv = Ws[(k4 * 4 + j) * 64 + lane];
        s0 = fmaf(((const float*)&a)[j], wv, s0);
        s1 = fmaf(((const float*)&b)[j], wv, s1);
        s2 = fmaf(((const float*)&c)[j], wv, s2);
        s3 = fmaf(((const float*)&d)[j], wv, s3);
      }
    }
    int ob = base * 64 + lane;
    h16[ob]       = __float2half(s0);
    h16[ob + 64]  = __float2half(s1);
    h16[ob + 128] = __float2half(s2);
    h16[ob + 192] = __float2half(s3);
    int head = lane >> 4;
    bool wr = (lane & 15) == 0;
#define RED16(v)                                                               \
    do {                                                                       \
      v += __shfl_xor(v, 1);                                                   \
      v += __shfl_xor(v, 2);                                                   \
      v += __shfl_xor(v, 4);                                                   \
      v += __shfl_xor(v, 8);                                                   \
    } while (0)
    float v;
    v = s0 * atts; RED16(v); if (wr) a_src[(base + 0) * 4 + head] = v;
    v = s0 * attd; RED16(v); if (wr) a_dst[(base + 0) * 4 + head] = v;
    v = s1 * atts; RED16(v); if (wr) a_src[(base + 1) * 4 + head] = v;
    v = s1 * attd; RED16(v); if (wr) a_dst[(base + 1) * 4 + head] = v;
    v = s2 * atts; RED16(v); if (wr) a_src[(base + 2) * 4 + head] = v;
    v = s2 * attd; RED16(v); if (wr) a_dst[(base + 2) * 4 + head] = v;
    v = s3 * atts; RED16(v); if (wr) a_src[(base + 3) * 4 + head] = v;
    v = s3 * attd; RED16(v); if (wr) a_dst[(base + 3) * 4 + head] = v;
#undef RED16
  }
}

// Per half-bucket (64 dst nodes): CSR in LDS (single buf read, reg replay),
// then GAT softmax+agg. grid = 2*NBUK; 256 threads = 4 waves.
__global__ __launch_bounds__(256) void k_gatb(
    const int* __restrict__ gcount, const int* __restrict__ buf,
    const __half* __restrict__ h16, const float* __restrict__ a_src,
    const float* __restrict__ a_dst, const float* __restrict__ bias,
    const float* __restrict__ w_rel, const float* __restrict__ w_root,
    const float* __restrict__ b_score, float* __restrict__ out_x,
    float* __restrict__ p, float* __restrict__ score) {
  __shared__ int ldeg[64];
  __shared__ int loff[64];
  __shared__ int lcur[64];
  __shared__ int lel[BC2];
  int bk = blockIdx.x >> 1;
  int half = blockIdx.x & 1;
  int tid = threadIdx.x;
  int lane = tid & 63, wid = tid >> 6;   // wid 0..3
  int n0 = (bk << 7) + (half << 6);
  int nnodes = NN - n0;
  if (nnodes <= 0) return;               // whole block exits (bk 781 half 1)
  if (nnodes > 64) nnodes = 64;
  int c = gcount[bk]; if (c > BCAP) c = BCAP;

  if (tid < 64) ldeg[tid] = 0;
  __syncthreads();
  // single read of this bucket's slice into registers
  int ent[RPT];
#pragma unroll
  for (int k = 0; k < RPT; ++k) {
    int idx = tid + k * 256;
    ent[k] = (idx < c) ? buf[bk * BCAP + idx] : -1;   // -1: r>>6 == -1, skipped
  }
#pragma unroll
  for (int k = 0; k < RPT; ++k) {
    int r = ent[k] >> 17;                             // arithmetic shift
    if ((r >> 6) == half) atomicAdd(&ldeg[r & 63], 1);
  }
  __syncthreads();
  // single-wave exclusive scan of ldeg[64]
  if (tid < 64) {
    int v = ldeg[tid];
    int inc = v;
#pragma unroll
    for (int o = 1; o < 64; o <<= 1) {
      int t = __shfl_up(inc, o);
      if (lane >= o) inc += t;
    }
    loff[tid] = inc - v;
    lcur[tid] = inc - v;
  }
  __syncthreads();
#pragma unroll
  for (int k = 0; k < RPT; ++k) {
    int entry = ent[k];
    int r = entry >> 17;
    if ((r >> 6) == half) {
      int pos = atomicAdd(&lcur[r & 63], 1);
      if (pos < BC2) lel[pos] = entry & 0x1FFFF;
    }
  }
  __syncthreads();

  // GAT phase: one wave per node, 4 waves round-robin
  int hsel = lane & 3;           // head, weight phase
  int esel = lane >> 2;          // edge slot, weight phase (0..15)
  int hl = lane & 31;            // feature-pair index
  int epar = lane >> 5;          // parallel-edge half in accum phase
  int ohead = hl >> 3;           // head owning feats 2hl,2hl+1
  for (int nl = wid; nl < nnodes; nl += 4) {
    int node = n0 + nl;
    int dg = ldeg[nl];
    int off = loff[nl];
    if (off + dg > BC2) dg = (BC2 > off) ? BC2 - off : 0;  // safety clamp
    float ad = a_dst[node * 4 + hsel];
    float ax0, ay0, ax1 = 0.f, ay1 = 0.f, ax2 = 0.f, ay2 = 0.f,
          ax3 = 0.f, ay3 = 0.f, zacc;
    {  // self-loop
      float l = a_src[node * 4 + hsel] + ad;
      l = l > 0.f ? l : NEG * l;
      float e = __expf(l);
      zacc = (esel == 0) ? e : 0.f;
      float lo = a_src[node * 4 + ohead] + a_dst[node * 4 + ohead];
      lo = lo > 0.f ? lo : NEG * lo;
      float eo = __expf(lo);
      __half2 hv = *reinterpret_cast<const __half2*>(h16 + node * 64 + 2 * hl);
      ax0 = (epar == 0) ? eo * __low2float(hv) : 0.f;
      ay0 = (epar == 0) ? eo * __high2float(hv) : 0.f;
    }
    for (int cb = 0; cb < dg; cb += 64) {
      int rem = dg - cb; if (rem > 64) rem = 64;
      int s_lane = (lane < rem) ? lel[off + cb + lane] : 0;
      for (int gb = 0; gb < rem; gb += 16) {
        // weights for 16 edges x 4 heads, lane-parallel
        int e = gb + esel;                 // <= 63
        int srcw = __shfl(s_lane, e);
        float w = 0.f;
        if (e < rem) {
          float l = a_src[srcw * 4 + hsel] + ad;
          l = l > 0.f ? l : NEG * l;
          w = __expf(l);
        }
        zacc += w;
        // accumulate 8 edges/iter: 4 independent gather+fma chains.
        // j3 = j+6+epar <= 15; OOR slots carry w == 0; s_lane[pad] = 0.
        int nrem = rem - gb; if (nrem > 16) nrem = 16;
        for (int j = 0; j < nrem; j += 8) {
          int j0 = j + epar, j1 = j + 2 + epar, j2 = j + 4 + epar,
              j3 = j + 6 + epar;
          float w0 = __shfl(w, j0 * 4 + ohead);
          float w1 = __shfl(w, j1 * 4 + ohead);
          float w2 = __shfl(w, j2 * 4 + ohead);
          float w3 = __shfl(w, j3 * 4 + ohead);
          int s0 = __shfl(s_lane, gb + j0);
          int s1 = __shfl(s_lane, gb + j1);
          int s2 = __shfl(s_lane, gb + j2);
          int s3 = __shfl(s_lane, gb + j3);
          __half2 hv0 = *reinterpret_cast<const __half2*>(h16 + s0 * 64 + 2 * hl);
          __half2 hv1 = *reinterpret_cast<const __half2*>(h16 + s1 * 64 + 2 * hl);
          __half2 hv2 = *reinterpret_cast<const __half2*>(h16 + s2 * 64 + 2 * hl);
          __half2 hv3 = *reinterpret_cast<const __half2*>(h16 + s3 * 64 + 2 * hl);
          ax0 = fmaf(w0, __low2float(hv0), ax0);
          ay0 = fmaf(w0, __high2float(hv0), ay0);
          ax1 = fmaf(w1, __low2float(hv1), ax1);
          ay1 = fmaf(w1, __high2float(hv1), ay1);
          ax2 = fmaf(w2, __low2float(hv2), ax2);
          ay2 = fmaf(w2, __high2float(hv2), ay2);
          ax3 = fmaf(w3, __low2float(hv3), ax3);
          ay3 = fmaf(w3, __high2float(hv3), ay3);
        }
      }
    }
    float acc_x = (ax0 + ax1) + (ax2 + ax3);
    float acc_y = (ay0 + ay1) + (ay2 + ay3);
    // merge edge halves; z across edge-slot dim
    acc_x += __shfl_xor(acc_x, 32);
    acc_y += __shfl_xor(acc_y, 32);
    zacc += __shfl_xor(zacc, 4);
    zacc += __shfl_xor(zacc, 8);
    zacc += __shfl_xor(zacc, 16);
    zacc += __shfl_xor(zacc, 32);
    float z = __shfl(zacc, ohead);

    float2 bv = ((const float2*)bias)[hl];
    float xgx = acc_x / z + bv.x;
    float xgy = acc_y / z + bv.y;
    float2 wrv = ((const float2*)w_rel)[hl];
    float2 wov = ((const float2*)w_root)[hl];
    float pp = xgx * wrv.x + xgy * wrv.y;
    float rr = xgx * wov.x + xgy * wov.y;
#pragma unroll
    for (int o = 1; o < 32; o <<= 1) {
      pp += __shfl_xor(pp, o);
      rr += __shfl_xor(rr, o);
    }
    if (lane == 0) {
      p[node] = pp;
      score[node] = rr + b_score[0];
    }
    if (epar == 0) {
      float2 xg = {xgx, xgy};
      *reinterpret_cast<float2*>(out_x + node * 64 + 2 * hl) = xg;
    }
  }
}

// score[dst] += sum_in p[src], per-bucket in LDS — no global atomics.
__global__ __launch_bounds__(512) void k_scat2(const int* __restrict__ gcount,
                                               const int* __restrict__ buf,
                                               const float* __restrict__ p,
                                               float* __restrict__ score) {
  __shared__ float sacc[128];
  int bk = blockIdx.x;
  int tid = threadIdx.x;
  if (tid < 128) sacc[tid] = 0.f;
  __syncthreads();
  int c = gcount[bk]; if (c > BCAP) c = BCAP;
  for (int i = tid; i < c; i += 512) {
    int entry = buf[bk * BCAP + i];
    atomicAdd(&sacc[entry >> 17], p[entry & 0x1FFFF]);
  }
  __syncthreads();
  int n = (bk << 7) + tid;
  if (tid < 128 && n < NN) score[n] += sacc[tid];
}

__device__ inline int lower_bound_i(const int* a, int n, int key) {
  int lo = 0, hi = n;
  while (lo < hi) {
    int mid = (lo + hi) >> 1;
    if (a[mid] < key) lo = mid + 1; else hi = mid;
  }
  return lo;
}

// one block per graph; batch is sorted. gout = (sum e*x)/(sum e).
__global__ __launch_bounds__(256) void k_pool(const float* __restrict__ xg,
                                              const float* __restrict__ score,
                                              const int* __restrict__ batch,
                                              float* __restrict__ gout) {
  int b = blockIdx.x;
  int lo = lower_bound_i(batch, NN, b);
  int hi = lower_bound_i(batch, NN, b + 1);
  int lane = threadIdx.x & 63;
  int w = threadIdx.x >> 6;
  float z = 0.f, vec = 0.f;
  for (int i = lo + w; i < hi; i += 4) {
    float e = __expf(score[i]);
    z += e;
    vec = fmaf(e, xg[(size_t)i * 64 + lane], vec);
  }
  __shared__ float zs[4];
  __shared__ float vs[4][64];
  if (lane == 0) zs[w] = z;
  vs[w][lane] = vec;
  __syncthreads();
  if (w == 0) {
    float zt = zs[0] + zs[1] + zs[2] + zs[3];
    float vt = vs[0][lane] + vs[1][lane] + vs[2][lane] + vs[3][lane];
    gout[(size_t)b * 64 + lane] = (hi > lo) ? vt / zt : 0.f;
  }
}

extern "C" void kernel_launch(void* const* d_in, const int* in_sizes, int n_in,
                              void* d_out, int out_size, void* d_ws,
                              size_t ws_size, hipStream_t stream) {
  (void)in_sizes; (void)n_in; (void)out_size; (void)ws_size;
  const float* x       = (const float*)d_in[0];
  const int*   ei      = (const int*)d_in[1];
  const int*   batch   = (const int*)d_in[2];
  const float* W       = (const float*)d_in[3];
  const float* att_src = (const float*)d_in[4];
  const float* att_dst = (const float*)d_in[5];
  const float* bias    = (const float*)d_in[6];
  const float* w_rel   = (const float*)d_in[7];
  const float* w_root  = (const float*)d_in[8];
  const float* b_score = (const float*)d_in[9];

  float* out_x = (float*)d_out;
  float* gout  = out_x + (size_t)NN * 64;

  char* wsp = (char*)d_ws;
  __half* h16  = (__half*)wsp; wsp += (size_t)NN * 64 * 2;
  float* a_src = (float*)wsp;  wsp += (size_t)NN * 4 * 4;
  float* a_dst = (float*)wsp;  wsp += (size_t)NN * 4 * 4;
  float* p     = (float*)wsp;  wsp += (size_t)NN * 4;
  float* score = (float*)wsp;  wsp += (size_t)NN * 4;
  int*   gcnt  = (int*)wsp;    wsp += (size_t)((NBUK + 127) / 128) * 128 * 4;
  int*   buf   = (int*)wsp;    wsp += (size_t)NBUK * BCAP * 4;

  hipMemsetAsync(gcnt, 0, NBUK * sizeof(int), stream);
  k_gc<<<NCHB + NGEMMB, 1024, 0, stream>>>(x, W, att_src, att_dst, h16,
                                           a_src, a_dst, ei, gcnt, buf);
  k_gatb<<<2 * NBUK, 256, 0, stream>>>(gcnt, buf, h16, a_src, a_dst, bias,
                                       w_rel, w_root, b_score, out_x, p, score);
  k_scat2<<<NBUK, 512, 0, stream>>>(gcnt, buf, p, score);
  k_pool<<<NBATCH, 256, 0, stream>>>(out_x, score, batch, gout);
}